// Round 4
// baseline (279.028 us; speedup 1.0000x reference)
//
#include <hip/hip_runtime.h>
#include <hip/hip_bf16.h>

// Problem dims
constexpr int BDIM = 16384;  // B (GEMM M)
constexpr int LDIM = 4096;   // L (GEMM N)
constexpr int HDIM = 1024;   // H (GEMM K)

// GEMM tile config: 256x256 tile, BK=64, 8 waves (2Mx4N), 2-deep dbuf,
// persistent: each block walks 4 N-adjacent tiles (same M panel).
constexpr int BM = 256;
constexpr int BN = 256;
constexpr int BK = 64;

typedef __attribute__((ext_vector_type(8))) __bf16 bf16x8;
typedef __attribute__((ext_vector_type(4))) float f32x4;

// ---------- fp32 -> bf16 (RNE) ----------
__device__ __forceinline__ unsigned short f2bf(float f) {
  unsigned int u = __float_as_uint(f);
  u += 0x7fffu + ((u >> 16) & 1u);
  return (unsigned short)(u >> 16);
}

// ---------- fused prep: convert A,W to bf16; bias[j] = W[j].E[j] + b[j] ----------
// blocks [0,1024): W rows (4 waves = 4 rows each) + bias reduction (shares W read)
// blocks [1024,3072): A flat convert, grid-stride
__global__ void prep_kernel(const float* __restrict__ A, const float* __restrict__ W,
                            const float* __restrict__ E, const float* __restrict__ b,
                            unsigned short* __restrict__ Ab, unsigned short* __restrict__ Wb,
                            float* __restrict__ bias) {
  const int bid = blockIdx.x;
  if (bid < 1024) {
    const int w = threadIdx.x >> 6;
    const int l = threadIdx.x & 63;
    const int row = bid * 4 + w;
    const float4* Wr = (const float4*)(W + (size_t)row * HDIM);
    const float4* Er = (const float4*)(E + (size_t)row * HDIM);
    ushort4* Wo = (ushort4*)(Wb + (size_t)row * HDIM);
    float s = 0.0f;
#pragma unroll
    for (int i = 0; i < HDIM / 256; ++i) {  // 4 iters
      float4 wv = Wr[i * 64 + l];
      float4 ev = Er[i * 64 + l];
      ushort4 r;
      r.x = f2bf(wv.x); r.y = f2bf(wv.y); r.z = f2bf(wv.z); r.w = f2bf(wv.w);
      Wo[i * 64 + l] = r;
      s += wv.x * ev.x + wv.y * ev.y + wv.z * ev.z + wv.w * ev.w;
    }
#pragma unroll
    for (int o = 32; o > 0; o >>= 1) s += __shfl_down(s, o, 64);
    if (l == 0) bias[row] = s + b[row];
  } else {
    const int nA4 = (BDIM * HDIM) >> 2;
    for (int i = (bid - 1024) * 256 + threadIdx.x; i < nA4; i += 2048 * 256) {
      float4 v = ((const float4*)A)[i];
      ushort4 r;
      r.x = f2bf(v.x); r.y = f2bf(v.y); r.z = f2bf(v.z); r.w = f2bf(v.w);
      ((ushort4*)Ab)[i] = r;
    }
  }
}

// ---------- GEMM: C[B,L] = Ab[B,H] * Wb[L,H]^T + bias[L] ----------
__device__ __forceinline__ void gld_lds16(const void* g, void* l) {
  __builtin_amdgcn_global_load_lds(
      (const __attribute__((address_space(1))) void*)g,
      (__attribute__((address_space(3))) void*)l, 16, 0, 0);
}

#define MEMPIN asm volatile("" ::: "memory")
#define BAR __builtin_amdgcn_s_barrier()
#define LGKM0 asm volatile("s_waitcnt lgkmcnt(0)" ::: "memory")
#define VM4 asm volatile("s_waitcnt vmcnt(4)" ::: "memory")
#define VM0 asm volatile("s_waitcnt vmcnt(0)" ::: "memory")
#define VMNONE (void)0

__global__ __launch_bounds__(512, 2) void gemm_kernel(
    const unsigned short* __restrict__ Ab,  // [BDIM, HDIM] bf16
    const unsigned short* __restrict__ Wb,  // [LDIM, HDIM] bf16
    const float* __restrict__ bias,         // [LDIM]
    float* __restrict__ C)                  // [BDIM, LDIM]
{
  __shared__ unsigned short As[2 * BM * BK];  // 64 KiB
  __shared__ unsigned short Bs[2 * BN * BK];  // 64 KiB

  const int tid = threadIdx.x;
  const int w = tid >> 6;
  const int l = tid & 63;
  const int wr = w >> 2;       // 0..1 : M half (128 rows)
  const int wc = w & 3;        // 0..3 : N quarter (64 cols)
  const int lr = l & 15;
  const int hi = l >> 4;

  // 256 persistent blocks: XCD swizzle (256 % 8 == 0 -> bijective).
  // swz -> (mblk 0..63, ngrp 0..3); block walks ntile = ngrp*4 + j, j=0..3.
  const int bid = blockIdx.x;
  const int swz = (bid & 7) * 32 + (bid >> 3);
  const int mblk = swz >> 2;
  const int ngrp = swz & 3;
  const int brow = mblk * BM;
  const int bcol0 = ngrp * 4 * BN;

  // staging source: thread t: row=t>>3 (0..63), chunk=(t&7)^(row&7) pre-swizzled
  const int srow = tid >> 3;
  const int scn = (tid & 7) ^ (srow & 7);
  const unsigned short* aSrc = Ab + (size_t)(brow + srow) * HDIM + scn * 8;
  const unsigned short* bSrc0 = Wb + (size_t)(bcol0 + srow) * HDIM + scn * 8;
  const int wdst = w * 512;

  // fragment-read constants (swizzled chunk offsets, shorts)
  const int c0 = ((hi) ^ (lr & 7)) * 8;
  const int c1 = ((4 + hi) ^ (lr & 7)) * 8;
  const int rowA = wr * 128 + lr;
  const int rowB = wc * 64 + lr;

  f32x4 acc[8][4] = {};
  bf16x8 aF[8];
  bf16x8 bF0[4], bF1[4];

#define ISSUE_A(d, h, kk)                                                      \
  { const unsigned short* s_ = aSrc + (size_t)((h) * 128) * HDIM + (kk) * BK;  \
    unsigned short* p_ = &As[(d) * 16384 + (h) * 8192 + wdst];                 \
    gld_lds16(s_, p_);                                                         \
    gld_lds16(s_ + (size_t)64 * HDIM, p_ + 4096); }
#define ISSUE_B(d, h, bp, kk)                                                  \
  { const unsigned short* s_ = (bp) + (size_t)((h) * 128) * HDIM + (kk) * BK;  \
    unsigned short* p_ = &Bs[(d) * 16384 + (h) * 8192 + wdst];                 \
    gld_lds16(s_, p_);                                                         \
    gld_lds16(s_ + (size_t)64 * HDIM, p_ + 4096); }

#define READ_A(d, h)                                                           \
  _Pragma("unroll") for (int mi = 0; mi < 4; ++mi) {                           \
    const int r_ = (d) * 16384 + (rowA + (h) * 64 + mi * 16) * BK;             \
    aF[mi * 2 + 0] = *(const bf16x8*)&As[r_ + c0];                             \
    aF[mi * 2 + 1] = *(const bf16x8*)&As[r_ + c1];                             \
  }
#define READ_B(d, g, BF)                                                       \
  _Pragma("unroll") for (int ni = 0; ni < 2; ++ni) {                           \
    const int r_ = (d) * 16384 + (rowB + (g) * 32 + ni * 16) * BK;             \
    BF[ni * 2 + 0] = *(const bf16x8*)&Bs[r_ + c0];                             \
    BF[ni * 2 + 1] = *(const bf16x8*)&Bs[r_ + c1];                             \
  }

#define MQUAD(h, g, BF)                                                        \
  __builtin_amdgcn_s_setprio(1);                                               \
  _Pragma("unroll") for (int mi = 0; mi < 4; ++mi) {                           \
    _Pragma("unroll") for (int ni = 0; ni < 2; ++ni) {                         \
      acc[(h) * 4 + mi][(g) * 2 + ni] = __builtin_amdgcn_mfma_f32_16x16x32_bf16( \
          aF[mi * 2 + 0], BF[ni * 2 + 0], acc[(h) * 4 + mi][(g) * 2 + ni], 0, 0, 0); \
      acc[(h) * 4 + mi][(g) * 2 + ni] = __builtin_amdgcn_mfma_f32_16x16x32_bf16( \
          aF[mi * 2 + 1], BF[ni * 2 + 1], acc[(h) * 4 + mi][(g) * 2 + ni], 0, 0, 0); \
    }                                                                          \
  }                                                                            \
  __builtin_amdgcn_s_setprio(0);

  // Per K-step (buf d): stage A(k+1)->d^1 at P1/P2, B(k+2)->d at P3/P4,
  // counted vmcnt(4) once per step at P4.
#define TILE(d, kA, bp, kB, SA, SB, VMW, LASTBAR)                              \
  { READ_A(d, 0) READ_B(d, 0, bF0)                                             \
    if (SA) ISSUE_A((d) ^ 1, 0, (kA));                                         \
    MEMPIN; BAR; LGKM0;                                                        \
    MQUAD(0, 0, bF0)                                                           \
    MEMPIN; BAR;                                                               \
    READ_B(d, 1, bF1)                                                          \
    if (SA) ISSUE_A((d) ^ 1, 1, (kA));                                         \
    MEMPIN; BAR; LGKM0;                                                        \
    MQUAD(0, 1, bF1)                                                           \
    MEMPIN; BAR;                                                               \
    READ_A(d, 1)                                                               \
    if (SB) ISSUE_B((d), 0, (bp), (kB));                                       \
    MEMPIN; BAR; LGKM0;                                                        \
    MQUAD(1, 1, bF1)                                                           \
    MEMPIN; BAR;                                                               \
    if (SB) ISSUE_B((d), 1, (bp), (kB));                                       \
    MEMPIN; BAR;                                                               \
    MQUAD(1, 0, bF0)                                                           \
    VMW;                                                                       \
    if (LASTBAR) BAR;                                                          \
    MEMPIN;                                                                    \
  }

  const int orow0 = brow + wr * 128 + hi * 4;
  const int ocolw = wc * 64 + lr;

  // epilogue for tile at bc: nontemporal stores (don't evict A/B panels), acc reset
#define EPI(bc)                                                                \
  { _Pragma("unroll") for (int mi = 0; mi < 8; ++mi) {                         \
      _Pragma("unroll") for (int ni = 0; ni < 4; ++ni) {                       \
        _Pragma("unroll") for (int r = 0; r < 4; ++r) {                        \
          __builtin_nontemporal_store(                                         \
              acc[mi][ni][r] + bv[ni],                                         \
              &C[(size_t)(orow0 + mi * 16 + r) * LDIM + (bc) + ocolw + ni * 16]); \
          acc[mi][ni][r] = 0.0f;                                               \
        }                                                                      \
      }                                                                        \
    } }

  // prologue: stage tile0 (A+B) and B(k=1); drain tile0, leave B(1) in flight
  ISSUE_A(0, 0, 0); ISSUE_A(0, 1, 0);
  ISSUE_B(0, 0, bSrc0, 0); ISSUE_B(0, 1, bSrc0, 0);
  ISSUE_B(1, 0, bSrc0, 1); ISSUE_B(1, 1, bSrc0, 1);
  VM4;
  MEMPIN; BAR;

#pragma unroll 1
  for (int j = 0; j < 4; ++j) {
    const unsigned short* bS0 = bSrc0 + (size_t)j * BN * HDIM;
    const unsigned short* bS1 = bS0 + (size_t)BN * HDIM;
    const int bc = bcol0 + j * BN;
    float bv[4];
#pragma unroll
    for (int ni = 0; ni < 4; ++ni) bv[ni] = bias[bc + ocolw + ni * 16];

#pragma unroll 1
    for (int p = 0; p < 7; ++p) {  // local k-steps 0..13
      TILE(0, 2 * p + 1, bS0, 2 * p + 2, 1, 1, VM4, 1);
      TILE(1, 2 * p + 2, bS0, 2 * p + 3, 1, 1, VM4, 1);
    }
    if (j < 3) {
      // local k-steps 14,15: B staging crosses into tile j+1 (bS1, k=0,1)
      TILE(0, 15, bS1, 0, 1, 1, VM4, 1);
      TILE(1, 0, bS1, 1, 1, 1, VM4, 1);
      EPI(bc);       // stores overlap staged-ahead loads
      VM0;           // drain stores (L2 ack) + in-flight stages to reset counts
      MEMPIN; BAR;
    } else {
      // final tile: peel, no further staging
      TILE(0, 15, bS1, 0, 1, 0, VM0, 1);
      TILE(1, 0, bS1, 0, 0, 0, VMNONE, 0);
      EPI(bc);
    }
  }
#undef EPI
#undef TILE
#undef MQUAD
#undef READ_A
#undef READ_B
#undef ISSUE_A
#undef ISSUE_B
}

extern "C" void kernel_launch(void* const* d_in, const int* in_sizes, int n_in,
                              void* d_out, int out_size, void* d_ws, size_t ws_size,
                              hipStream_t stream) {
  const float* bert = (const float*)d_in[0];  // [B,H]
  const float* emb  = (const float*)d_in[1];  // [L,H]
  const float* W    = (const float*)d_in[2];  // [L,H]
  const float* b    = (const float*)d_in[3];  // [L]
  float* out = (float*)d_out;

  char* ws = (char*)d_ws;
  unsigned short* Ab = (unsigned short*)ws;
  unsigned short* Wb = (unsigned short*)(ws + (size_t)BDIM * HDIM * 2);
  float* bias = (float*)(ws + (size_t)BDIM * HDIM * 2 + (size_t)LDIM * HDIM * 2);

  hipLaunchKernelGGL(prep_kernel, dim3(3072), dim3(256), 0, stream,
                     bert, W, emb, b, Ab, Wb, bias);
  hipLaunchKernelGGL(gemm_kernel, dim3(256), dim3(512), 0, stream,
                     Ab, Wb, bias, out);
}

// Round 5
// 139.528 us; speedup vs baseline: 1.9998x; 1.9998x over previous
//
#include <hip/hip_runtime.h>
#include <hip/hip_bf16.h>

// Problem dims
constexpr int BDIM = 16384;  // B (GEMM M)
constexpr int LDIM = 4096;   // L (GEMM N)
constexpr int HDIM = 1024;   // H (GEMM K)

// GEMM tile: 256x256, BK=64 (i8), 8 waves (2Mx4N), 2-deep dbuf, 2 phases/tile
constexpr int BM = 256;
constexpr int BN = 256;
constexpr int BK = 64;
constexpr int KTILES = HDIM / BK;  // 16

typedef __attribute__((ext_vector_type(4))) int i32x4;

// ---------- prep: per-row i8 quant of A and W; bias[j] = W[j].E[j] + b[j] ----------
// blocks [0,1024): W rows (4/block) + bias dot (exact fp32, shares W read)
// blocks [1024,5120): A rows (4/block)
__global__ void prep_kernel(const float* __restrict__ A, const float* __restrict__ W,
                            const float* __restrict__ E, const float* __restrict__ b,
                            signed char* __restrict__ Aq, signed char* __restrict__ Wq,
                            float* __restrict__ sA, float* __restrict__ sW,
                            float* __restrict__ bias) {
  const int bid = blockIdx.x;
  const int w = threadIdx.x >> 6;
  const int l = threadIdx.x & 63;
  const bool isW = bid < (LDIM / 4);
  const int row = isW ? bid * 4 + w : (bid - LDIM / 4) * 4 + w;
  const float4* s4 = (const float4*)((isW ? W : A) + (size_t)row * HDIM);

  float4 v[4];
  float amax = 0.f, dot = 0.f;
#pragma unroll
  for (int i = 0; i < 4; ++i) {
    v[i] = s4[i * 64 + l];
    amax = fmaxf(amax, fmaxf(fmaxf(fabsf(v[i].x), fabsf(v[i].y)),
                             fmaxf(fabsf(v[i].z), fabsf(v[i].w))));
  }
  if (isW) {
    const float4* e4 = (const float4*)(E + (size_t)row * HDIM);
#pragma unroll
    for (int i = 0; i < 4; ++i) {
      float4 ev = e4[i * 64 + l];
      dot += v[i].x * ev.x + v[i].y * ev.y + v[i].z * ev.z + v[i].w * ev.w;
    }
  }
#pragma unroll
  for (int o = 32; o > 0; o >>= 1) amax = fmaxf(amax, __shfl_xor(amax, o, 64));
  if (isW) {
#pragma unroll
    for (int o = 32; o > 0; o >>= 1) dot += __shfl_xor(dot, o, 64);
  }
  const float inv = amax > 0.f ? 127.f / amax : 0.f;
  unsigned int* dst =
      (unsigned int*)((isW ? Wq : Aq) + (size_t)row * HDIM);
#pragma unroll
  for (int i = 0; i < 4; ++i) {
    int q0 = (int)rintf(v[i].x * inv), q1 = (int)rintf(v[i].y * inv);
    int q2 = (int)rintf(v[i].z * inv), q3 = (int)rintf(v[i].w * inv);
    dst[i * 64 + l] =
        (q0 & 255) | ((q1 & 255) << 8) | ((q2 & 255) << 16) | ((q3 & 255) << 24);
  }
  if (l == 0) {
    if (isW) { sW[row] = amax * (1.f / 127.f); bias[row] = dot + b[row]; }
    else sA[row] = amax * (1.f / 127.f);
  }
}

// ---------- GEMM: C[B,L] = sA*sW*(Aq[B,H] . Wq[L,H]^T) + bias[L] ----------
__device__ __forceinline__ void gld_lds16(const void* g, void* l) {
  __builtin_amdgcn_global_load_lds(
      (const __attribute__((address_space(1))) void*)g,
      (__attribute__((address_space(3))) void*)l, 16, 0, 0);
}

#define MEMPIN asm volatile("" ::: "memory")
#define BAR __builtin_amdgcn_s_barrier()
#define LGKM0 asm volatile("s_waitcnt lgkmcnt(0)" ::: "memory")
#define VM2 asm volatile("s_waitcnt vmcnt(2)" ::: "memory")
#define VM0 asm volatile("s_waitcnt vmcnt(0)" ::: "memory")
#define VMNONE (void)0

__global__ __launch_bounds__(512, 2) void gemm_kernel(
    const signed char* __restrict__ Aq,  // [BDIM, HDIM] i8
    const signed char* __restrict__ Wq,  // [LDIM, HDIM] i8
    const float* __restrict__ sA,        // [BDIM]
    const float* __restrict__ sW,        // [LDIM]
    const float* __restrict__ bias,      // [LDIM]
    float* __restrict__ C)               // [BDIM, LDIM]
{
  // 2-deep dbuf, each: 256 rows x 64B = 16 KiB. 32 KiB per matrix, 64 KiB total.
  __shared__ __attribute__((aligned(128))) signed char As[2 * BM * BK];
  __shared__ __attribute__((aligned(128))) signed char Bs[2 * BN * BK];

  const int tid = threadIdx.x;
  const int w = tid >> 6;
  const int l = tid & 63;
  const int wr = w >> 2;       // 0..1 : M half (128 rows)
  const int wc = w & 3;        // 0..3 : N quarter (64 cols)
  const int lr = l & 15;
  const int hi = l >> 4;

  // XCD-aware swizzle (1024 blocks, %8==0 -> bijective)
  const int bid = blockIdx.x;
  const int swz = (bid & 7) * 128 + (bid >> 3);
  const int mblk = swz >> 4;
  const int nblk = swz & 15;
  const int brow = mblk * BM;
  const int bcol = nblk * BN;

  // staging: one gld_lds16 = 512thr x 16B = 8 KiB = 128 rows x 64B.
  // thread t: row = t>>2, chunk = t&3; source chunk pre-swizzled by
  // c ^ ((row>>1)&3)  (involution; read side uses the same XOR -> 2-way max)
  const int srow = tid >> 2;                       // 0..127
  const int scn = (tid & 3) ^ ((tid >> 3) & 3);
  const signed char* aSrc = Aq + (size_t)(brow + srow) * HDIM + scn * 16;
  const signed char* bSrc = Wq + (size_t)(bcol + srow) * HDIM + scn * 16;

  // fragment-read byte offset within a 64B row: k-chunk hi, XOR row bits 1..2
  const int c0 = (hi ^ ((lr >> 1) & 3)) * 16;
  const int rowA = wr * 128 + lr;
  const int rowB = wc * 64 + lr;

  i32x4 acc[8][4] = {};
  i32x4 aF[4], bF0[2], bF1[2];

#define ISSUE_A(d, kk)                                                         \
  { const signed char* s_ = aSrc + (kk) * BK;                                  \
    gld_lds16(s_, &As[(d) * 16384 + w * 1024]);                                \
    gld_lds16(s_ + (size_t)128 * HDIM, &As[(d) * 16384 + 8192 + w * 1024]); }
#define ISSUE_B(d, kk)                                                         \
  { const signed char* s_ = bSrc + (kk) * BK;                                  \
    gld_lds16(s_, &Bs[(d) * 16384 + w * 1024]);                                \
    gld_lds16(s_ + (size_t)128 * HDIM, &Bs[(d) * 16384 + 8192 + w * 1024]); }

#define READ_A(d, h)                                                           \
  _Pragma("unroll") for (int mi = 0; mi < 4; ++mi) {                           \
    aF[mi] = *(const i32x4*)&As[(d) * 16384 +                                  \
                                (rowA + (h) * 64 + mi * 16) * 64 + c0];        \
  }
#define READ_B(d, g, BF)                                                       \
  _Pragma("unroll") for (int ni = 0; ni < 2; ++ni) {                           \
    BF[ni] = *(const i32x4*)&Bs[(d) * 16384 +                                  \
                                (rowB + (g) * 32 + ni * 16) * 64 + c0];        \
  }

#define MQUAD(h, g, BF)                                                        \
  _Pragma("unroll") for (int mi = 0; mi < 4; ++mi) {                           \
    _Pragma("unroll") for (int ni = 0; ni < 2; ++ni) {                         \
      acc[(h) * 4 + mi][(g) * 2 + ni] = __builtin_amdgcn_mfma_i32_16x16x64_i8( \
          aF[mi], BF[ni], acc[(h) * 4 + mi][(g) * 2 + ni], 0, 0, 0);           \
    }                                                                          \
  }

  // tile t in buf d: PH1 {read A.h0+B.g0+B.g1, stage A(t+1)->d^1, bar, 16 MFMA,
  // bar}; PH2 {read A.h1, stage B(t+2)->d, bar, 16 MFMA, vmcnt(2), bar}
#define TILE(d, tA, tB, SA, SB, VMW, LASTBAR)                                  \
  { READ_A(d, 0) READ_B(d, 0, bF0) READ_B(d, 1, bF1)                           \
    if (SA) ISSUE_A((d) ^ 1, (tA));                                            \
    MEMPIN; BAR; LGKM0;                                                        \
    __builtin_amdgcn_s_setprio(1);                                             \
    MQUAD(0, 0, bF0) MQUAD(0, 1, bF1)                                          \
    __builtin_amdgcn_s_setprio(0);                                             \
    MEMPIN; BAR;                                                               \
    READ_A(d, 1)                                                               \
    if (SB) ISSUE_B((d), (tB));                                                \
    MEMPIN; BAR; LGKM0;                                                        \
    __builtin_amdgcn_s_setprio(1);                                             \
    MQUAD(1, 1, bF1) MQUAD(1, 0, bF0)                                          \
    __builtin_amdgcn_s_setprio(0);                                             \
    VMW;                                                                       \
    if (LASTBAR) BAR;                                                          \
    MEMPIN;                                                                    \
  }

  // prologue: A(0)->b0, B(0)->b0, B(1)->b1; drain tile0 (leave B(1) in flight)
  ISSUE_A(0, 0); ISSUE_B(0, 0); ISSUE_B(1, 1);
  VM2;
  MEMPIN; BAR;

#pragma unroll 1
  for (int t = 0; t < KTILES - 2; t += 2) {
    TILE(0, t + 1, t + 2, 1, 1, VM2, 1);
    TILE(1, t + 2, t + 3, 1, 1, VM2, 1);
  }
  TILE(0, KTILES - 1, 0, 1, 0, VM0, 1);  // stages A(15); drains everything
  TILE(1, 0, 0, 0, 0, VMNONE, 0);

  // epilogue: dequant out = sA[r]*sW[c]*acc + bias[c]
  float sw4[4], bv[4];
#pragma unroll
  for (int ni = 0; ni < 4; ++ni) {
    const int cc = bcol + wc * 64 + ni * 16 + lr;
    sw4[ni] = sW[cc];
    bv[ni] = bias[cc];
  }
  const int orow0 = brow + wr * 128 + hi * 4;
  const int ocol0 = bcol + wc * 64 + lr;
#pragma unroll
  for (int mi = 0; mi < 8; ++mi) {
#pragma unroll
    for (int r = 0; r < 4; ++r) {
      const float sa = sA[orow0 + mi * 16 + r];
#pragma unroll
      for (int ni = 0; ni < 4; ++ni) {
        C[(size_t)(orow0 + mi * 16 + r) * LDIM + ocol0 + ni * 16] =
            (float)acc[mi][ni][r] * (sa * sw4[ni]) + bv[ni];
      }
    }
  }
#undef TILE
#undef MQUAD
#undef READ_A
#undef READ_B
#undef ISSUE_A
#undef ISSUE_B
}

extern "C" void kernel_launch(void* const* d_in, const int* in_sizes, int n_in,
                              void* d_out, int out_size, void* d_ws, size_t ws_size,
                              hipStream_t stream) {
  const float* bert = (const float*)d_in[0];  // [B,H]
  const float* emb  = (const float*)d_in[1];  // [L,H]
  const float* W    = (const float*)d_in[2];  // [L,H]
  const float* b    = (const float*)d_in[3];  // [L]
  float* out = (float*)d_out;

  // ws layout: Aq 16MB | Wq 4MB | sA 64KB | sW 16KB | bias 16KB
  char* ws = (char*)d_ws;
  signed char* Aq = (signed char*)ws;
  signed char* Wq = (signed char*)(ws + (size_t)BDIM * HDIM);
  float* sAp  = (float*)(ws + (size_t)BDIM * HDIM + (size_t)LDIM * HDIM);
  float* sWp  = (float*)((char*)sAp + BDIM * sizeof(float));
  float* bias = (float*)((char*)sWp + LDIM * sizeof(float));

  hipLaunchKernelGGL(prep_kernel, dim3(LDIM / 4 + BDIM / 4), dim3(256), 0, stream,
                     bert, W, emb, b, Aq, Wq, sAp, sWp, bias);
  hipLaunchKernelGGL(gemm_kernel, dim3((BDIM / BM) * (LDIM / BN)), dim3(512), 0, stream,
                     Aq, Wq, sAp, sWp, bias, out);
}

// Round 7
// 135.963 us; speedup vs baseline: 2.0522x; 1.0262x over previous
//
#include <hip/hip_runtime.h>
#include <hip/hip_bf16.h>

// Problem dims
constexpr int BDIM = 16384;  // B (GEMM M)
constexpr int LDIM = 4096;   // L (GEMM N)
constexpr int HDIM = 1024;   // H (GEMM K)

// GEMM tile: 256x128, BK=64 (i8), 8 waves (4Mx2N), wave tile 64x64.
// A: 2-deep dbuf. B: 4-slot ring (stage distance +2 needs ring >= 3; 4 for
// power-of-2 period). ONE barrier per K-tile. 2 blocks/CU resident.
constexpr int BM = 256;
constexpr int BN = 128;
constexpr int BK = 64;
constexpr int KTILES = HDIM / BK;  // 16

typedef __attribute__((ext_vector_type(4))) int i32x4;

// ---------- prep: per-row i8 quant of A and W; bias[j] = W[j].E[j] + b[j] ----------
__global__ void prep_kernel(const float* __restrict__ A, const float* __restrict__ W,
                            const float* __restrict__ E, const float* __restrict__ b,
                            signed char* __restrict__ Aq, signed char* __restrict__ Wq,
                            float* __restrict__ sA, float* __restrict__ sW,
                            float* __restrict__ bias) {
  const int bid = blockIdx.x;
  const int w = threadIdx.x >> 6;
  const int l = threadIdx.x & 63;
  const bool isW = bid < (LDIM / 4);
  const int row = isW ? bid * 4 + w : (bid - LDIM / 4) * 4 + w;
  const float4* s4 = (const float4*)((isW ? W : A) + (size_t)row * HDIM);

  float4 v[4];
  float amax = 0.f, dot = 0.f;
#pragma unroll
  for (int i = 0; i < 4; ++i) {
    v[i] = s4[i * 64 + l];
    amax = fmaxf(amax, fmaxf(fmaxf(fabsf(v[i].x), fabsf(v[i].y)),
                             fmaxf(fabsf(v[i].z), fabsf(v[i].w))));
  }
  if (isW) {
    const float4* e4 = (const float4*)(E + (size_t)row * HDIM);
#pragma unroll
    for (int i = 0; i < 4; ++i) {
      float4 ev = e4[i * 64 + l];
      dot += v[i].x * ev.x + v[i].y * ev.y + v[i].z * ev.z + v[i].w * ev.w;
    }
  }
#pragma unroll
  for (int o = 32; o > 0; o >>= 1) amax = fmaxf(amax, __shfl_xor(amax, o, 64));
  if (isW) {
#pragma unroll
    for (int o = 32; o > 0; o >>= 1) dot += __shfl_xor(dot, o, 64);
  }
  const float inv = amax > 0.f ? 127.f / amax : 0.f;
  unsigned int* dst = (unsigned int*)((isW ? Wq : Aq) + (size_t)row * HDIM);
#pragma unroll
  for (int i = 0; i < 4; ++i) {
    int q0 = (int)rintf(v[i].x * inv), q1 = (int)rintf(v[i].y * inv);
    int q2 = (int)rintf(v[i].z * inv), q3 = (int)rintf(v[i].w * inv);
    dst[i * 64 + l] =
        (q0 & 255) | ((q1 & 255) << 8) | ((q2 & 255) << 16) | ((q3 & 255) << 24);
  }
  if (l == 0) {
    if (isW) { sW[row] = amax * (1.f / 127.f); bias[row] = dot + b[row]; }
    else sA[row] = amax * (1.f / 127.f);
  }
}

// ---------- GEMM: C[B,L] = sA*sW*(Aq[B,H] . Wq[L,H]^T) + bias[L] ----------
__device__ __forceinline__ void gld_lds16(const void* g, void* l) {
  __builtin_amdgcn_global_load_lds(
      (const __attribute__((address_space(1))) void*)g,
      (__attribute__((address_space(3))) void*)l, 16, 0, 0);
}

#define MEMPIN asm volatile("" ::: "memory")
#define SCHED0 __builtin_amdgcn_sched_barrier(0)
#define BAR __builtin_amdgcn_s_barrier()
#define LGKM0 asm volatile("s_waitcnt lgkmcnt(0)" ::: "memory")
#define VM1 asm volatile("s_waitcnt vmcnt(1)" ::: "memory")
#define VM0 asm volatile("s_waitcnt vmcnt(0)" ::: "memory")
#define VMNONE (void)0

__global__ __launch_bounds__(512, 4) void gemm_kernel(
    const signed char* __restrict__ Aq,  // [BDIM, HDIM] i8
    const signed char* __restrict__ Wq,  // [LDIM, HDIM] i8
    const float* __restrict__ sA,        // [BDIM]
    const float* __restrict__ sW,        // [LDIM]
    const float* __restrict__ bias,      // [LDIM]
    float* __restrict__ C)               // [BDIM, LDIM]
{
  // As: 2 x 16KB dbuf. Bs: 4 x 8KB ring. 64 KiB total -> 2 blocks/CU.
  __shared__ __attribute__((aligned(128))) signed char As[2 * BM * BK];
  __shared__ __attribute__((aligned(128))) signed char Bs[4 * BN * BK];

  const int tid = threadIdx.x;
  const int w = tid >> 6;
  const int l = tid & 63;
  const int wr = w >> 1;       // 0..3 : M quarter (64 rows)
  const int wc = w & 1;        // 0..1 : N half (64 cols)
  const int lr = l & 15;
  const int hi = l >> 4;

  // XCD-aware swizzle (2048 blocks, %8==0 -> bijective). nblk inner: each
  // XCD sweeps W (4MB i8, L2-resident) against one A panel (256KB, L2-hot).
  const int bid = blockIdx.x;
  const int swz = (bid & 7) * 256 + (bid >> 3);
  const int mblk = swz >> 5;   // 64
  const int nblk = swz & 31;   // 32
  const int brow = mblk * BM;
  const int bcol = nblk * BN;

  // staging: one gld_lds16 = 512thr x 16B = 8 KiB = 128 rows x 64B.
  // thread t: row=t>>2, chunk=(t&3)^((row>>1)&3) pre-swizzled (involution).
  const int srow = tid >> 2;                      // 0..127
  const int scn = (tid & 3) ^ ((tid >> 3) & 3);
  const signed char* aSrc = Aq + (size_t)(brow + srow) * HDIM + scn * 16;
  const signed char* bSrc = Wq + (size_t)(bcol + srow) * HDIM + scn * 16;

  // fragment-read byte offset within a 64B row (same XOR on read side)
  const int c0 = (hi ^ ((lr >> 1) & 3)) * 16;
  const int rowA = wr * 64 + lr;
  const int rowB = wc * 64 + lr;

  i32x4 acc[4][4] = {};
  i32x4 aF[4], bF[4];

#define ISSUE_A(d, kk)                                                         \
  { const signed char* s_ = aSrc + (kk) * BK;                                  \
    gld_lds16(s_, &As[(d) * 16384 + w * 1024]);                                \
    gld_lds16(s_ + (size_t)128 * HDIM, &As[(d) * 16384 + 8192 + w * 1024]); }
#define ISSUE_B(s, kk)                                                         \
  gld_lds16(bSrc + (kk) * BK, &Bs[(s) * 8192 + w * 1024]);

#define READ_AB(d, s)                                                          \
  _Pragma("unroll") for (int mi = 0; mi < 4; ++mi)                             \
    aF[mi] = *(const i32x4*)&As[(d) * 16384 + (rowA + mi * 16) * 64 + c0];     \
  _Pragma("unroll") for (int ni = 0; ni < 4; ++ni)                             \
    bF[ni] = *(const i32x4*)&Bs[(s) * 8192 + (rowB + ni * 16) * 64 + c0];

#define MFMA16                                                                 \
  _Pragma("unroll") for (int mi = 0; mi < 4; ++mi) {                           \
    _Pragma("unroll") for (int ni = 0; ni < 4; ++ni) {                         \
      acc[mi][ni] = __builtin_amdgcn_mfma_i32_16x16x64_i8(                     \
          aF[mi], bF[ni], acc[mi][ni], 0, 0, 0);                               \
    }                                                                          \
  }

  // region t (A buf d = t&1, B slot s = t&3):
  //   ds_read A/B of this tile; stage A(t+1)->d^1 (safe: d^1's readers
  //   drained before last barrier); lgkm0; 16 MFMA; stage B(t+2)->slot
  //   (t+2)&3 (first reader 2 barriers away -> no WAR race); counted vmcnt
  //   (leaves only B(t+2) in flight); ONE barrier.
#define TILE(d, s, SA, tA, SB, sB, tB, VMW, DOBAR)                             \
  { READ_AB(d, s)                                                              \
    if (SA) ISSUE_A((d) ^ 1, (tA));                                            \
    SCHED0; LGKM0; SCHED0;                                                     \
    __builtin_amdgcn_s_setprio(1);                                             \
    MFMA16                                                                     \
    __builtin_amdgcn_s_setprio(0);                                             \
    SCHED0;                                                                    \
    if (SB) ISSUE_B((sB), (tB));                                               \
    VMW; MEMPIN;                                                               \
    if (DOBAR) BAR;                                                            \
    MEMPIN; }

  // prologue: A(0)->buf0 (2 loads), B(0)->slot0, B(1)->slot1.
  // VM1 leaves B(1) in flight; A(0),B(0) landed.
  ISSUE_A(0, 0); ISSUE_B(0, 0); ISSUE_B(1, 1);
  VM1;
  MEMPIN; BAR;

  // main: tiles 0..11 (period lcm(2,4)=4)
#pragma unroll 1
  for (int t = 0; t < 12; t += 4) {
    TILE(0, 0, 1, t + 1, 1, 2, t + 2, VM1, 1);
    TILE(1, 1, 1, t + 2, 1, 3, t + 3, VM1, 1);
    TILE(0, 2, 1, t + 3, 1, 0, t + 4, VM1, 1);
    TILE(1, 3, 1, t + 4, 1, 1, t + 5, VM1, 1);
  }
  // peel: tiles 12..15 (B(14),B(15) staged at t=12,13; then drain)
  TILE(0, 0, 1, 13, 1, 2, 14, VM1, 1);
  TILE(1, 1, 1, 14, 1, 3, 15, VM1, 1);
  TILE(0, 2, 1, 15, 0, 0, 0, VM0, 1);
  TILE(1, 3, 0, 0, 0, 0, 0, VMNONE, 0);

  // epilogue: dequant out = sA[r]*sW[c]*acc + bias[c]
  float sw4[4], bv[4];
#pragma unroll
  for (int ni = 0; ni < 4; ++ni) {
    const int cc = bcol + wc * 64 + ni * 16 + lr;
    sw4[ni] = sW[cc];
    bv[ni] = bias[cc];
  }
  const int orow0 = brow + wr * 64 + hi * 4;
  const int ocol0 = bcol + wc * 64 + lr;
#pragma unroll
  for (int mi = 0; mi < 4; ++mi) {
#pragma unroll
    for (int r = 0; r < 4; ++r) {
      const float sa = sA[orow0 + mi * 16 + r];
#pragma unroll
      for (int ni = 0; ni < 4; ++ni) {
        C[(size_t)(orow0 + mi * 16 + r) * LDIM + ocol0 + ni * 16] =
            (float)acc[mi][ni][r] * (sa * sw4[ni]) + bv[ni];
      }
    }
  }
#undef TILE
#undef MFMA16
#undef READ_AB
#undef ISSUE_A
#undef ISSUE_B
}

extern "C" void kernel_launch(void* const* d_in, const int* in_sizes, int n_in,
                              void* d_out, int out_size, void* d_ws, size_t ws_size,
                              hipStream_t stream) {
  const float* bert = (const float*)d_in[0];  // [B,H]
  const float* emb  = (const float*)d_in[1];  // [L,H]
  const float* W    = (const float*)d_in[2];  // [L,H]
  const float* b    = (const float*)d_in[3];  // [L]
  float* out = (float*)d_out;

  // ws layout: Aq 16MB | Wq 4MB | sA 64KB | sW 16KB | bias 16KB
  char* ws = (char*)d_ws;
  signed char* Aq = (signed char*)ws;
  signed char* Wq = (signed char*)(ws + (size_t)BDIM * HDIM);
  float* sAp  = (float*)(ws + (size_t)BDIM * HDIM + (size_t)LDIM * HDIM);
  float* sWp  = (float*)((char*)sAp + BDIM * sizeof(float));
  float* bias = (float*)((char*)sWp + LDIM * sizeof(float));

  hipLaunchKernelGGL(prep_kernel, dim3(LDIM / 4 + BDIM / 4), dim3(256), 0, stream,
                     bert, W, emb, b, Aq, Wq, sAp, sWp, bias);
  hipLaunchKernelGGL(gemm_kernel, dim3((BDIM / BM) * (LDIM / BN)), dim3(512), 0, stream,
                     Aq, Wq, sAp, sWp, bias, out);
}